// Round 5
// baseline (186.157 us; speedup 1.0000x reference)
//
#include <hip/hip_runtime.h>
#include <hip/hip_bf16.h>

// Problem constants: M=100000 points, K=27 offsets, Cin=Cout=64.
#define NPTS 100000
#define KOFF 27
#define KPAD 28          // padded K: tile 27 = zero weights + zero-row gathers
#define KHALF 14         // K-split: waves 0-3 do ko 0..13, waves 4-7 do 14..27
#define NCH  64

typedef __attribute__((ext_vector_type(8))) short bf16x8;   // 8 bf16 in 4 VGPRs
typedef __attribute__((ext_vector_type(8))) unsigned short u16x8;
typedef __attribute__((ext_vector_type(4))) float f32x4;

static __device__ __forceinline__ unsigned short f2bf(float x) {
  union { float f; unsigned int u; } v; v.f = x;
  unsigned int r = v.u + 0x7fffu + ((v.u >> 16) & 1u);   // RTNE
  return (unsigned short)(r >> 16);
}

// feats fp32 (M x 64) -> bf16 (M+1 x 64); row NPTS is all-zero (gather target
// for invalid rulebook entries).
__global__ void convert_feats_kernel(const float* __restrict__ feats,
                                     unsigned short* __restrict__ fb) {
  size_t tid  = (size_t)blockIdx.x * blockDim.x + threadIdx.x;
  size_t base = tid * 8;
  const size_t valid_total = (size_t)NPTS * NCH;
  const size_t total       = valid_total + NCH;
  if (base >= total) return;
  u16x8 r;
  if (base < valid_total) {
    const float4 a = *reinterpret_cast<const float4*>(feats + base);
    const float4 b = *reinterpret_cast<const float4*>(feats + base + 4);
    r[0] = f2bf(a.x); r[1] = f2bf(a.y); r[2] = f2bf(a.z); r[3] = f2bf(a.w);
    r[4] = f2bf(b.x); r[5] = f2bf(b.y); r[6] = f2bf(b.z); r[7] = f2bf(b.w);
  } else {
    #pragma unroll
    for (int j = 0; j < 8; ++j) r[j] = 0;
  }
  *reinterpret_cast<u16x8*>(fb + base) = r;
}

// weight fp32 [k][cin][cout] -> bf16 lane-major fragment layout:
// (ko, c, o) -> u16 index (ko*8 + (o>>4)*2 + (c>>5))*512
//               + (((c>>3)&3)*16 + (o&15))*8 + (c&7)
// Each MFMA B-fragment is one contiguous 1KB block, lane L's 16B at L*16.
// Pad tile 27 is zeros.
__global__ void convert_weight_kernel(const float* __restrict__ w,
                                      unsigned short* __restrict__ wt) {
  int tid = blockIdx.x * 256 + threadIdx.x;
  if (tid >= KPAD * NCH * NCH) return;
  int ko  = tid >> 12;
  int rem = tid & 4095;
  int c   = rem >> 6;
  int o   = rem & 63;
  unsigned short val = 0;
  if (ko < KOFF) val = f2bf(w[(size_t)ko * 4096 + c * 64 + o]);
  int dst = (ko * 8 + (o >> 4) * 2 + (c >> 5)) * 512
          + (((c >> 3) & 3) * 16 + (o & 15)) * 8 + (c & 7);
  wt[dst] = val;
}

// Main kernel: block = 128 rows, 8 waves (512 threads), K-split x2.
// Wave w: kgroup = w>>2 (ko range kgroup*14..+14), row-group rg = w&3
// (rows rg*32..rg*32+32, as 2 row-tiles of 16). Partial sums from kgroup 1
// are combined via padded LDS then kgroup-0 waves run the epilogue.
// B-fragments: contiguous 1KB lane-major vmem loads (L1/L2-resident).
// MFMA 16x16x32 bf16: A[i][k]: i=lane&15, k=8*(lane>>4)+j; B same k, n=lane&15;
// D[i][n]: n=lane&15, i=4*(lane>>4)+reg.
__global__ __launch_bounds__(512, 6)
void spconv_kernel(const unsigned short* __restrict__ fb,      // (NPTS+1) x 64 bf16
                   const int* __restrict__ rulebook,           // NPTS x 27 int32
                   const unsigned short* __restrict__ wl,      // lane-major weights
                   const float* __restrict__ feats,            // NPTS x 64 fp32
                   const float* __restrict__ bias,             // 64 fp32
                   float* __restrict__ out) {                  // NPTS x 64 fp32
  __shared__ int   s_off[128][KPAD];   // BYTE offsets into fb (idx*128)
  __shared__ int   s_cnt[128];
  __shared__ float s_red[128][65];     // kgroup-1 partial sums (padded stride)

  const int tid = threadIdx.x;
  const int m0  = blockIdx.x * 128;

  if (tid < 128) s_cnt[tid] = 0;
  __syncthreads();

  for (int f = tid; f < 128 * KPAD; f += 512) {
    int r = f / KPAD, k = f - r * KPAD;
    int m = m0 + r;
    int off = NPTS * 128;
    if (m < NPTS && k < KOFF) {
      int v = rulebook[(size_t)m * KOFF + k];
      if (v >= 0) { off = v * 128; atomicAdd(&s_cnt[r], 1); }
    }
    s_off[r][k] = off;
  }
  __syncthreads();

  const int wave   = tid >> 6;
  const int kgroup = wave >> 2;        // 0 or 1
  const int rg     = wave & 3;         // row group
  const int kbase  = kgroup * KHALF;
  const int lane = tid & 63;
  const int lr   = lane & 15;
  const int lk   = lane >> 4;
  const int coff_b = lk * 16;          // byte offset within 64B half-row
  const int row0 = rg * 32 + lr;
  const int row1 = rg * 32 + 16 + lr;

  const char* fbase = (const char*)fb;

  f32x4 acc0[4] = {f32x4{0,0,0,0}, f32x4{0,0,0,0}, f32x4{0,0,0,0}, f32x4{0,0,0,0}};
  f32x4 acc1[4] = {f32x4{0,0,0,0}, f32x4{0,0,0,0}, f32x4{0,0,0,0}, f32x4{0,0,0,0}};

  // Depth-2 gather pipeline regs.
  bf16x8 s0t0h0, s0t0h1, s0t1h0, s0t1h1;
  bf16x8 s1t0h0, s1t0h1, s1t1h0, s1t1h1;

#define GATHER(T0H0, T0H1, T1H0, T1H1, KO) {                                  \
    const char* p0_ = fbase + (size_t)(unsigned)s_off[row0][(KO)];            \
    const char* p1_ = fbase + (size_t)(unsigned)s_off[row1][(KO)];            \
    T0H0 = *reinterpret_cast<const bf16x8*>(p0_ + coff_b);                    \
    T0H1 = *reinterpret_cast<const bf16x8*>(p0_ + 64 + coff_b);               \
    T1H0 = *reinterpret_cast<const bf16x8*>(p1_ + coff_b);                    \
    T1H1 = *reinterpret_cast<const bf16x8*>(p1_ + 64 + coff_b);               \
  }

#define COMPUTE(T0H0, T0H1, T1H0, T1H1, KO) {                                 \
    const unsigned short* wb_ = wl + (size_t)(KO) * 4096 + lane * 8;          \
    _Pragma("unroll")                                                         \
    for (int nt = 0; nt < 4; ++nt) {                                          \
      const bf16x8 b0_ = *reinterpret_cast<const bf16x8*>(wb_ + (nt*2+0)*512);\
      const bf16x8 b1_ = *reinterpret_cast<const bf16x8*>(wb_ + (nt*2+1)*512);\
      acc0[nt] = __builtin_amdgcn_mfma_f32_16x16x32_bf16(T0H0, b0_, acc0[nt],0,0,0);\
      acc0[nt] = __builtin_amdgcn_mfma_f32_16x16x32_bf16(T0H1, b1_, acc0[nt],0,0,0);\
      acc1[nt] = __builtin_amdgcn_mfma_f32_16x16x32_bf16(T1H0, b0_, acc1[nt],0,0,0);\
      acc1[nt] = __builtin_amdgcn_mfma_f32_16x16x32_bf16(T1H1, b1_, acc1[nt],0,0,0);\
    }                                                                         \
  }

  GATHER(s0t0h0, s0t0h1, s0t1h0, s0t1h1, kbase + 0)
  GATHER(s1t0h0, s1t0h1, s1t1h0, s1t1h1, kbase + 1)

  #pragma unroll 1
  for (int i = 0; i < KHALF; i += 2) {
    COMPUTE(s0t0h0, s0t0h1, s0t1h0, s0t1h1, kbase + i)
    if (i + 2 < KHALF) GATHER(s0t0h0, s0t0h1, s0t1h0, s0t1h1, kbase + i + 2)
    COMPUTE(s1t0h0, s1t0h1, s1t1h0, s1t1h1, kbase + i + 1)
    if (i + 3 < KHALF) GATHER(s1t0h0, s1t0h1, s1t1h0, s1t1h1, kbase + i + 3)
  }
#undef GATHER
#undef COMPUTE

  // K-split reduction: kgroup 1 parks partials in LDS.
  if (kgroup == 1) {
    #pragma unroll
    for (int rt = 0; rt < 2; ++rt) {
      #pragma unroll
      for (int nt = 0; nt < 4; ++nt) {
        #pragma unroll
        for (int i = 0; i < 4; ++i) {
          const int rl = rg * 32 + rt * 16 + lk * 4 + i;
          s_red[rl][nt * 16 + lr] = (rt == 0) ? acc0[nt][i] : acc1[nt][i];
        }
      }
    }
  }
  __syncthreads();

  // Epilogue (kgroup 0 only): sum halves, /denom + bias + residual.
  if (kgroup == 0) {
    #pragma unroll
    for (int rt = 0; rt < 2; ++rt) {
      #pragma unroll
      for (int nt = 0; nt < 4; ++nt) {
        const int col = nt * 16 + lr;
        const float b = bias[col];
        #pragma unroll
        for (int i = 0; i < 4; ++i) {
          const int rl = rg * 32 + rt * 16 + lk * 4 + i;
          const int m  = m0 + rl;
          if (m < NPTS) {
            const float denom = (float)max(s_cnt[rl], 1);
            const float a = ((rt == 0) ? acc0[nt][i] : acc1[nt][i]) + s_red[rl][col];
            out[(size_t)m * NCH + col] =
                a / denom + b + feats[(size_t)m * NCH + col];
          }
        }
      }
    }
  }
}

extern "C" void kernel_launch(void* const* d_in, const int* in_sizes, int n_in,
                              void* d_out, int out_size, void* d_ws, size_t ws_size,
                              hipStream_t stream) {
  const float* feats    = (const float*)d_in[0];
  const int*   rulebook = (const int*)d_in[1];
  const float* weight   = (const float*)d_in[2];
  const float* bias     = (const float*)d_in[3];
  float* out = (float*)d_out;

  unsigned short* fb = (unsigned short*)d_ws;
  const size_t fb_bytes = (size_t)(NPTS + 1) * NCH * sizeof(unsigned short);
  const size_t wt_off   = (fb_bytes + 255) & ~(size_t)255;
  unsigned short* wl = (unsigned short*)((char*)d_ws + wt_off);

  {
    const size_t total = (size_t)(NPTS + 1) * NCH;
    const int threads = (int)((total + 7) / 8);
    convert_feats_kernel<<<(threads + 255) / 256, 256, 0, stream>>>(feats, fb);
  }
  {
    const int n = KPAD * NCH * NCH;
    convert_weight_kernel<<<(n + 255) / 256, 256, 0, stream>>>(weight, wl);
  }
  {
    const int nblk = (NPTS + 127) / 128;   // 782
    spconv_kernel<<<nblk, 512, 0, stream>>>(fb, rulebook, wl, feats, bias, out);
  }
}

// Round 6
// 121.937 us; speedup vs baseline: 1.5267x; 1.5267x over previous
//
#include <hip/hip_runtime.h>
#include <hip/hip_bf16.h>

// Problem constants: M=100000 points, K=27 offsets, Cin=Cout=64.
#define NPTS 100000
#define KOFF 27
#define KPAD 28          // padded K: tile 27 = zero weights + zero-row gathers
#define KHALF 14         // K-split: waves 0-3 do ko 0..13, waves 4-7 do 14..27
#define NCH  64

typedef __attribute__((ext_vector_type(8))) short bf16x8;   // 8 bf16 in 4 VGPRs
typedef __attribute__((ext_vector_type(8))) unsigned short u16x8;
typedef __attribute__((ext_vector_type(4))) float f32x4;

static __device__ __forceinline__ unsigned short f2bf(float x) {
  union { float f; unsigned int u; } v; v.f = x;
  unsigned int r = v.u + 0x7fffu + ((v.u >> 16) & 1u);   // RTNE
  return (unsigned short)(r >> 16);
}

// feats fp32 (M x 64) -> bf16 (M+1 x 64); row NPTS is all-zero (gather target
// for invalid rulebook entries).
__global__ void convert_feats_kernel(const float* __restrict__ feats,
                                     unsigned short* __restrict__ fb) {
  size_t tid  = (size_t)blockIdx.x * blockDim.x + threadIdx.x;
  size_t base = tid * 8;
  const size_t valid_total = (size_t)NPTS * NCH;
  const size_t total       = valid_total + NCH;
  if (base >= total) return;
  u16x8 r;
  if (base < valid_total) {
    const float4 a = *reinterpret_cast<const float4*>(feats + base);
    const float4 b = *reinterpret_cast<const float4*>(feats + base + 4);
    r[0] = f2bf(a.x); r[1] = f2bf(a.y); r[2] = f2bf(a.z); r[3] = f2bf(a.w);
    r[4] = f2bf(b.x); r[5] = f2bf(b.y); r[6] = f2bf(b.z); r[7] = f2bf(b.w);
  } else {
    #pragma unroll
    for (int j = 0; j < 8; ++j) r[j] = 0;
  }
  *reinterpret_cast<u16x8*>(fb + base) = r;
}

// weight fp32 [k][cin][cout] -> bf16 lane-major fragment layout:
// (ko, c, o) -> u16 index (ko*8 + (o>>4)*2 + (c>>5))*512
//               + (((c>>3)&3)*16 + (o&15))*8 + (c&7)
// Each MFMA B-fragment is one contiguous 1KB block, lane L's 16B at L*16.
// Pad tile 27 is zeros.
__global__ void convert_weight_kernel(const float* __restrict__ w,
                                      unsigned short* __restrict__ wt) {
  int tid = blockIdx.x * 256 + threadIdx.x;
  if (tid >= KPAD * NCH * NCH) return;
  int ko  = tid >> 12;
  int rem = tid & 4095;
  int c   = rem >> 6;
  int o   = rem & 63;
  unsigned short val = 0;
  if (ko < KOFF) val = f2bf(w[(size_t)ko * 4096 + c * 64 + o]);
  int dst = (ko * 8 + (o >> 4) * 2 + (c >> 5)) * 512
          + (((c >> 3) & 3) * 16 + (o & 15)) * 8 + (c & 7);
  wt[dst] = val;
}

// Main kernel: block = 128 rows, 8 waves (512 threads), K-split x2.
// Wave w: kgroup = w>>2 (ko range kgroup*14..+14), row-group rg = w&3
// (rows rg*32..rg*32+32 as 2 row-tiles of 16). kgroup-1 partials go through
// padded LDS; kgroup-0 waves run the epilogue.
// NOTE: no min-waves launch_bounds — R5 showed (512,6) caps VGPR at 40 and
// spills acc+pipeline regs to scratch (FETCH +138MB/dispatch).
__global__ __launch_bounds__(512)
void spconv_kernel(const unsigned short* __restrict__ fb,      // (NPTS+1) x 64 bf16
                   const int* __restrict__ rulebook,           // NPTS x 27 int32
                   const unsigned short* __restrict__ wl,      // lane-major weights
                   const float* __restrict__ feats,            // NPTS x 64 fp32
                   const float* __restrict__ bias,             // 64 fp32
                   float* __restrict__ out) {                  // NPTS x 64 fp32
  __shared__ int   s_off[128][KPAD];   // BYTE offsets into fb (idx*128)
  __shared__ int   s_cnt[128];
  __shared__ float s_red[128][65];     // kgroup-1 partial sums (padded stride)

  const int tid = threadIdx.x;
  const int m0  = blockIdx.x * 128;

  if (tid < 128) s_cnt[tid] = 0;
  __syncthreads();

  for (int f = tid; f < 128 * KPAD; f += 512) {
    int r = f / KPAD, k = f - r * KPAD;
    int m = m0 + r;
    int off = NPTS * 128;
    if (m < NPTS && k < KOFF) {
      int v = rulebook[(size_t)m * KOFF + k];
      if (v >= 0) { off = v * 128; atomicAdd(&s_cnt[r], 1); }
    }
    s_off[r][k] = off;
  }
  __syncthreads();

  const int wave   = tid >> 6;
  const int kgroup = wave >> 2;        // 0 or 1
  const int rg     = wave & 3;         // row group
  const int kbase  = kgroup * KHALF;
  const int lane = tid & 63;
  const int lr   = lane & 15;
  const int lk   = lane >> 4;
  const int coff_b = lk * 16;          // byte offset within 64B half-row
  const int row0 = rg * 32 + lr;
  const int row1 = rg * 32 + 16 + lr;

  const char* fbase = (const char*)fb;

  f32x4 acc0[4] = {f32x4{0,0,0,0}, f32x4{0,0,0,0}, f32x4{0,0,0,0}, f32x4{0,0,0,0}};
  f32x4 acc1[4] = {f32x4{0,0,0,0}, f32x4{0,0,0,0}, f32x4{0,0,0,0}, f32x4{0,0,0,0}};

  // Depth-2 gather pipeline regs.
  bf16x8 s0t0h0, s0t0h1, s0t1h0, s0t1h1;
  bf16x8 s1t0h0, s1t0h1, s1t1h0, s1t1h1;

#define GATHER(T0H0, T0H1, T1H0, T1H1, KO) {                                  \
    const char* p0_ = fbase + (size_t)(unsigned)s_off[row0][(KO)];            \
    const char* p1_ = fbase + (size_t)(unsigned)s_off[row1][(KO)];            \
    T0H0 = *reinterpret_cast<const bf16x8*>(p0_ + coff_b);                    \
    T0H1 = *reinterpret_cast<const bf16x8*>(p0_ + 64 + coff_b);               \
    T1H0 = *reinterpret_cast<const bf16x8*>(p1_ + coff_b);                    \
    T1H1 = *reinterpret_cast<const bf16x8*>(p1_ + 64 + coff_b);               \
  }

#define COMPUTE(T0H0, T0H1, T1H0, T1H1, KO) {                                 \
    const unsigned short* wb_ = wl + (size_t)(KO) * 4096 + lane * 8;          \
    _Pragma("unroll")                                                         \
    for (int nt = 0; nt < 4; ++nt) {                                          \
      const bf16x8 b0_ = *reinterpret_cast<const bf16x8*>(wb_ + (nt*2+0)*512);\
      const bf16x8 b1_ = *reinterpret_cast<const bf16x8*>(wb_ + (nt*2+1)*512);\
      acc0[nt] = __builtin_amdgcn_mfma_f32_16x16x32_bf16(T0H0, b0_, acc0[nt],0,0,0);\
      acc0[nt] = __builtin_amdgcn_mfma_f32_16x16x32_bf16(T0H1, b1_, acc0[nt],0,0,0);\
      acc1[nt] = __builtin_amdgcn_mfma_f32_16x16x32_bf16(T1H0, b0_, acc1[nt],0,0,0);\
      acc1[nt] = __builtin_amdgcn_mfma_f32_16x16x32_bf16(T1H1, b1_, acc1[nt],0,0,0);\
    }                                                                         \
  }

  GATHER(s0t0h0, s0t0h1, s0t1h0, s0t1h1, kbase + 0)
  GATHER(s1t0h0, s1t0h1, s1t1h0, s1t1h1, kbase + 1)

  #pragma unroll 1
  for (int i = 0; i < KHALF; i += 2) {
    COMPUTE(s0t0h0, s0t0h1, s0t1h0, s0t1h1, kbase + i)
    if (i + 2 < KHALF) GATHER(s0t0h0, s0t0h1, s0t1h0, s0t1h1, kbase + i + 2)
    COMPUTE(s1t0h0, s1t0h1, s1t1h0, s1t1h1, kbase + i + 1)
    if (i + 3 < KHALF) GATHER(s1t0h0, s1t0h1, s1t1h0, s1t1h1, kbase + i + 3)
  }
#undef GATHER
#undef COMPUTE

  // K-split reduction: kgroup 1 parks partials in LDS.
  if (kgroup == 1) {
    #pragma unroll
    for (int rt = 0; rt < 2; ++rt) {
      #pragma unroll
      for (int nt = 0; nt < 4; ++nt) {
        #pragma unroll
        for (int i = 0; i < 4; ++i) {
          const int rl = rg * 32 + rt * 16 + lk * 4 + i;
          s_red[rl][nt * 16 + lr] = (rt == 0) ? acc0[nt][i] : acc1[nt][i];
        }
      }
    }
  }
  __syncthreads();

  // Epilogue (kgroup 0 only): sum halves, /denom + bias + residual.
  if (kgroup == 0) {
    #pragma unroll
    for (int rt = 0; rt < 2; ++rt) {
      #pragma unroll
      for (int nt = 0; nt < 4; ++nt) {
        const int col = nt * 16 + lr;
        const float b = bias[col];
        #pragma unroll
        for (int i = 0; i < 4; ++i) {
          const int rl = rg * 32 + rt * 16 + lk * 4 + i;
          const int m  = m0 + rl;
          if (m < NPTS) {
            const float denom = (float)max(s_cnt[rl], 1);
            const float a = ((rt == 0) ? acc0[nt][i] : acc1[nt][i]) + s_red[rl][col];
            out[(size_t)m * NCH + col] =
                a / denom + b + feats[(size_t)m * NCH + col];
          }
        }
      }
    }
  }
}

extern "C" void kernel_launch(void* const* d_in, const int* in_sizes, int n_in,
                              void* d_out, int out_size, void* d_ws, size_t ws_size,
                              hipStream_t stream) {
  const float* feats    = (const float*)d_in[0];
  const int*   rulebook = (const int*)d_in[1];
  const float* weight   = (const float*)d_in[2];
  const float* bias     = (const float*)d_in[3];
  float* out = (float*)d_out;

  unsigned short* fb = (unsigned short*)d_ws;
  const size_t fb_bytes = (size_t)(NPTS + 1) * NCH * sizeof(unsigned short);
  const size_t wt_off   = (fb_bytes + 255) & ~(size_t)255;
  unsigned short* wl = (unsigned short*)((char*)d_ws + wt_off);

  {
    const size_t total = (size_t)(NPTS + 1) * NCH;
    const int threads = (int)((total + 7) / 8);
    convert_feats_kernel<<<(threads + 255) / 256, 256, 0, stream>>>(feats, fb);
  }
  {
    const int n = KPAD * NCH * NCH;
    convert_weight_kernel<<<(n + 255) / 256, 256, 0, stream>>>(weight, wl);
  }
  {
    const int nblk = (NPTS + 127) / 128;   // 782
    spconv_kernel<<<nblk, 512, 0, stream>>>(fb, rulebook, wl, feats, bias, out);
  }
}

// Round 7
// 106.828 us; speedup vs baseline: 1.7426x; 1.1414x over previous
//
#include <hip/hip_runtime.h>
#include <hip/hip_bf16.h>

// Problem constants: M=100000 points, K=27 offsets, Cin=Cout=64.
#define NPTS 100000
#define KOFF 27
#define KPAD 28          // padded K: tile 27 = zero weights + zero-row gathers
#define NCH  64

typedef __attribute__((ext_vector_type(8))) short bf16x8;   // 8 bf16 in 4 VGPRs
typedef __attribute__((ext_vector_type(8))) unsigned short u16x8;
typedef __attribute__((ext_vector_type(4))) float f32x4;

static __device__ __forceinline__ unsigned short f2bf(float x) {
  union { float f; unsigned int u; } v; v.f = x;
  unsigned int r = v.u + 0x7fffu + ((v.u >> 16) & 1u);   // RTNE
  return (unsigned short)(r >> 16);
}

// feats fp32 (M x 64) -> bf16 (M+1 x 64); row NPTS is all-zero (gather target
// for invalid rulebook entries).
__global__ void convert_feats_kernel(const float* __restrict__ feats,
                                     unsigned short* __restrict__ fb) {
  size_t tid  = (size_t)blockIdx.x * blockDim.x + threadIdx.x;
  size_t base = tid * 8;
  const size_t valid_total = (size_t)NPTS * NCH;
  const size_t total       = valid_total + NCH;
  if (base >= total) return;
  u16x8 r;
  if (base < valid_total) {
    const float4 a = *reinterpret_cast<const float4*>(feats + base);
    const float4 b = *reinterpret_cast<const float4*>(feats + base + 4);
    r[0] = f2bf(a.x); r[1] = f2bf(a.y); r[2] = f2bf(a.z); r[3] = f2bf(a.w);
    r[4] = f2bf(b.x); r[5] = f2bf(b.y); r[6] = f2bf(b.z); r[7] = f2bf(b.w);
  } else {
    #pragma unroll
    for (int j = 0; j < 8; ++j) r[j] = 0;
  }
  *reinterpret_cast<u16x8*>(fb + base) = r;
}

// weight fp32 [k][cin][cout] -> bf16 lane-major fragment layout:
// (ko, c, o) -> u16 index (ko*8 + (o>>4)*2 + (c>>5))*512
//               + (((c>>3)&3)*16 + (o&15))*8 + (c&7)
// Each MFMA B-fragment is one contiguous 1KB block, lane L's 16B at L*16.
// Pad tile 27 is zeros.
__global__ void convert_weight_kernel(const float* __restrict__ w,
                                      unsigned short* __restrict__ wt) {
  int tid = blockIdx.x * 256 + threadIdx.x;
  if (tid >= KPAD * NCH * NCH) return;
  int ko  = tid >> 12;
  int rem = tid & 4095;
  int c   = rem >> 6;
  int o   = rem & 63;
  unsigned short val = 0;
  if (ko < KOFF) val = f2bf(w[(size_t)ko * 4096 + c * 64 + o]);
  int dst = (ko * 8 + (o >> 4) * 2 + (c >> 5)) * 512
          + (((c >> 3) & 3) * 16 + (o & 15)) * 8 + (c & 7);
  wt[dst] = val;
}

// Main kernel: block = 128 rows, 4 waves (256 thr); wave owns 32 rows
// (2 row-tiles of 16) x 64 cout x all 28 kos.
// vmcnt-retire-order-aware pipeline: per ko, MFMA(ko) consumes A+B loaded
// earlier; THEN reload B(ko+1) (single reg set), THEN issue A(ko+2), THEN
// ds_read offsets for ko+4. The youngest batch any MFMA drains through is its
// own B-batch (~1 MFMA-block old, L2-resident); A-gathers are always older so
// their latency is fully pipelined — never drained early.
__global__ __launch_bounds__(256, 4)
void spconv_kernel(const unsigned short* __restrict__ fb,      // (NPTS+1) x 64 bf16
                   const int* __restrict__ rulebook,           // NPTS x 27 int32
                   const unsigned short* __restrict__ wl,      // lane-major weights
                   const float* __restrict__ feats,            // NPTS x 64 fp32
                   const float* __restrict__ bias,             // 64 fp32
                   float* __restrict__ out) {                  // NPTS x 64 fp32
  __shared__ int s_off[128][KPAD];   // BYTE offsets into fb (idx*128)
  __shared__ int s_cnt[128];

  const int tid = threadIdx.x;
  const int m0  = blockIdx.x * 128;

  if (tid < 128) s_cnt[tid] = 0;
  __syncthreads();

  for (int f = tid; f < 128 * KPAD; f += 256) {
    int r = f / KPAD, k = f - r * KPAD;
    int m = m0 + r;
    int off = NPTS * 128;
    if (m < NPTS && k < KOFF) {
      int v = rulebook[(size_t)m * KOFF + k];
      if (v >= 0) { off = v * 128; atomicAdd(&s_cnt[r], 1); }
    }
    s_off[r][k] = off;
  }
  __syncthreads();

  const int wave = tid >> 6;
  const int lane = tid & 63;
  const int lr   = lane & 15;
  const int lk   = lane >> 4;
  const int coff_b = lk * 16;          // byte offset within 64B half-row
  const int row0 = wave * 32 + lr;
  const int row1 = wave * 32 + 16 + lr;

  const char* fbase = (const char*)fb;
  const unsigned short* wlane = wl + lane * 8;

  f32x4 acc0[4] = {f32x4{0,0,0,0}, f32x4{0,0,0,0}, f32x4{0,0,0,0}, f32x4{0,0,0,0}};
  f32x4 acc1[4] = {f32x4{0,0,0,0}, f32x4{0,0,0,0}, f32x4{0,0,0,0}, f32x4{0,0,0,0}};

  // A pipeline: 2 sets (distance 2 over ko).
  bf16x8 A0t0h0, A0t0h1, A0t1h0, A0t1h1;   // even kos
  bf16x8 A1t0h0, A1t0h1, A1t1h0, A1t1h1;   // odd kos
  // B: single set, reloaded each ko after consumption.
  bf16x8 B0, B1, B2, B3, B4, B5, B6, B7;
  // Offset regs (per-lane), distance-2 prefetch feeding the A loads.
  int oa0, oa1, ob0, ob1;

#define LOADA(T0H0, T0H1, T1H0, T1H1, O0, O1) {                               \
    const char* p0_ = fbase + (size_t)(unsigned)(O0);                         \
    const char* p1_ = fbase + (size_t)(unsigned)(O1);                         \
    T0H0 = *reinterpret_cast<const bf16x8*>(p0_ + coff_b);                    \
    T0H1 = *reinterpret_cast<const bf16x8*>(p0_ + 64 + coff_b);               \
    T1H0 = *reinterpret_cast<const bf16x8*>(p1_ + coff_b);                    \
    T1H1 = *reinterpret_cast<const bf16x8*>(p1_ + 64 + coff_b);               \
  }

#define LOADB(KO) {                                                           \
    const unsigned short* wb_ = wlane + (size_t)(KO) * 4096;                  \
    B0 = *reinterpret_cast<const bf16x8*>(wb_ + 0 * 512);                     \
    B1 = *reinterpret_cast<const bf16x8*>(wb_ + 1 * 512);                     \
    B2 = *reinterpret_cast<const bf16x8*>(wb_ + 2 * 512);                     \
    B3 = *reinterpret_cast<const bf16x8*>(wb_ + 3 * 512);                     \
    B4 = *reinterpret_cast<const bf16x8*>(wb_ + 4 * 512);                     \
    B5 = *reinterpret_cast<const bf16x8*>(wb_ + 5 * 512);                     \
    B6 = *reinterpret_cast<const bf16x8*>(wb_ + 6 * 512);                     \
    B7 = *reinterpret_cast<const bf16x8*>(wb_ + 7 * 512);                     \
  }

#define MFMA_STEP(T0H0, T0H1, T1H0, T1H1) {                                   \
    acc0[0] = __builtin_amdgcn_mfma_f32_16x16x32_bf16(T0H0, B0, acc0[0],0,0,0);\
    acc0[0] = __builtin_amdgcn_mfma_f32_16x16x32_bf16(T0H1, B1, acc0[0],0,0,0);\
    acc1[0] = __builtin_amdgcn_mfma_f32_16x16x32_bf16(T1H0, B0, acc1[0],0,0,0);\
    acc1[0] = __builtin_amdgcn_mfma_f32_16x16x32_bf16(T1H1, B1, acc1[0],0,0,0);\
    acc0[1] = __builtin_amdgcn_mfma_f32_16x16x32_bf16(T0H0, B2, acc0[1],0,0,0);\
    acc0[1] = __builtin_amdgcn_mfma_f32_16x16x32_bf16(T0H1, B3, acc0[1],0,0,0);\
    acc1[1] = __builtin_amdgcn_mfma_f32_16x16x32_bf16(T1H0, B2, acc1[1],0,0,0);\
    acc1[1] = __builtin_amdgcn_mfma_f32_16x16x32_bf16(T1H1, B3, acc1[1],0,0,0);\
    acc0[2] = __builtin_amdgcn_mfma_f32_16x16x32_bf16(T0H0, B4, acc0[2],0,0,0);\
    acc0[2] = __builtin_amdgcn_mfma_f32_16x16x32_bf16(T0H1, B5, acc0[2],0,0,0);\
    acc1[2] = __builtin_amdgcn_mfma_f32_16x16x32_bf16(T1H0, B4, acc1[2],0,0,0);\
    acc1[2] = __builtin_amdgcn_mfma_f32_16x16x32_bf16(T1H1, B5, acc1[2],0,0,0);\
    acc0[3] = __builtin_amdgcn_mfma_f32_16x16x32_bf16(T0H0, B6, acc0[3],0,0,0);\
    acc0[3] = __builtin_amdgcn_mfma_f32_16x16x32_bf16(T0H1, B7, acc0[3],0,0,0);\
    acc1[3] = __builtin_amdgcn_mfma_f32_16x16x32_bf16(T1H0, B6, acc1[3],0,0,0);\
    acc1[3] = __builtin_amdgcn_mfma_f32_16x16x32_bf16(T1H1, B7, acc1[3],0,0,0);\
  }

  // Prologue: A(0), A(1) in flight; B(0) in flight; offsets for ko 2,3 cached.
  oa0 = s_off[row0][0]; oa1 = s_off[row1][0];
  ob0 = s_off[row0][1]; ob1 = s_off[row1][1];
  LOADA(A0t0h0, A0t0h1, A0t1h0, A0t1h1, oa0, oa1)
  LOADA(A1t0h0, A1t0h1, A1t1h0, A1t1h1, ob0, ob1)
  LOADB(0)
  oa0 = s_off[row0][2]; oa1 = s_off[row1][2];
  ob0 = s_off[row0][3]; ob1 = s_off[row1][3];

  #pragma unroll 1
  for (int kk = 0; kk < KPAD / 2; ++kk) {
    const int ko = kk * 2;
    // ---- even ko ----
    MFMA_STEP(A0t0h0, A0t0h1, A0t1h0, A0t1h1)          // consumes A(ko), B(ko)
    LOADB(ko + 1)                                      // refill B (single set)
    if (ko + 2 < KPAD) {
      LOADA(A0t0h0, A0t0h1, A0t1h0, A0t1h1, oa0, oa1)  // A(ko+2)
    }
    if (ko + 4 < KPAD) {
      oa0 = s_off[row0][ko + 4]; oa1 = s_off[row1][ko + 4];
    }
    // ---- odd ko ----
    MFMA_STEP(A1t0h0, A1t0h1, A1t1h0, A1t1h1)          // consumes A(ko+1), B(ko+1)
    if (ko + 2 < KPAD) LOADB(ko + 2)
    if (ko + 3 < KPAD) {
      LOADA(A1t0h0, A1t0h1, A1t1h0, A1t1h1, ob0, ob1)  // A(ko+3)
    }
    if (ko + 5 < KPAD) {
      ob0 = s_off[row0][ko + 5]; ob1 = s_off[row1][ko + 5];
    }
  }
#undef LOADA
#undef LOADB
#undef MFMA_STEP

  // Epilogue: /denom + bias + residual.
  #pragma unroll
  for (int rt = 0; rt < 2; ++rt) {
    #pragma unroll
    for (int nt = 0; nt < 4; ++nt) {
      const int col = nt * 16 + lr;
      const float b = bias[col];
      #pragma unroll
      for (int i = 0; i < 4; ++i) {
        const int rl = wave * 32 + rt * 16 + lk * 4 + i;
        const int m  = m0 + rl;
        if (m < NPTS) {
          const float denom = (float)max(s_cnt[rl], 1);
          const float a = (rt == 0) ? acc0[nt][i] : acc1[nt][i];
          out[(size_t)m * NCH + col] =
              a / denom + b + feats[(size_t)m * NCH + col];
        }
      }
    }
  }
}

extern "C" void kernel_launch(void* const* d_in, const int* in_sizes, int n_in,
                              void* d_out, int out_size, void* d_ws, size_t ws_size,
                              hipStream_t stream) {
  const float* feats    = (const float*)d_in[0];
  const int*   rulebook = (const int*)d_in[1];
  const float* weight   = (const float*)d_in[2];
  const float* bias     = (const float*)d_in[3];
  float* out = (float*)d_out;

  unsigned short* fb = (unsigned short*)d_ws;
  const size_t fb_bytes = (size_t)(NPTS + 1) * NCH * sizeof(unsigned short);
  const size_t wt_off   = (fb_bytes + 255) & ~(size_t)255;
  unsigned short* wl = (unsigned short*)((char*)d_ws + wt_off);

  {
    const size_t total = (size_t)(NPTS + 1) * NCH;
    const int threads = (int)((total + 7) / 8);
    convert_feats_kernel<<<(threads + 255) / 256, 256, 0, stream>>>(feats, fb);
  }
  {
    const int n = KPAD * NCH * NCH;
    convert_weight_kernel<<<(n + 255) / 256, 256, 0, stream>>>(weight, wl);
  }
  {
    const int nblk = (NPTS + 127) / 128;   // 782
    spconv_kernel<<<nblk, 256, 0, stream>>>(fb, rulebook, wl, feats, bias, out);
  }
}